// Round 5
// baseline (2552.108 us; speedup 1.0000x reference)
//
#include <hip/hip_runtime.h>

#define NB_PTS 4096   // points per cloud
#define MB_SEL 1024   // centroids per cloud
#define KNBR   64     // max neighbors
#define NCLOUD 4
#define NCENT  (NCLOUD * MB_SEL)   // 4096 centroids total

// exact np-order squared distance in f64: ((dx*dx + dy*dy) + dz*dz), no FMA
__device__ __forceinline__ double d2_np64(double dx, double dy, double dz) {
  return __dadd_rn(__dadd_rn(__dmul_rn(dx, dx), __dmul_rn(dy, dy)),
                   __dmul_rn(dz, dz));
}

// ---------------------------------------------------------------------------
// Kernel 1: farthest point sampling (f64, matches f64 np golden reference).
// One block (1024 thr) per cloud. sel[k] stored as an exact small float into
// the batch_out region of d_out (values < 4096); conv_kernel consumes it and
// finally overwrites the region with (float)batch.
// ---------------------------------------------------------------------------
__global__ __launch_bounds__(1024) void fps_kernel(const float* __restrict__ pos,
                                                   float* __restrict__ selstash) {
  __shared__ float px[NB_PTS], py[NB_PTS], pz[NB_PTS];
  __shared__ double redv[16];
  __shared__ int    redi[16];
  __shared__ int    winner;
  const int b    = blockIdx.x;
  const int tid  = threadIdx.x;
  const int lane = tid & 63;
  const int wid  = tid >> 6;

  double mx[4], my[4], mz[4], dist[4];
#pragma unroll
  for (int q = 0; q < 4; ++q) {
    int j = tid + q * 1024;
    size_t base = ((size_t)b * NB_PTS + j) * 3;
    float X = pos[base], Y = pos[base + 1], Z = pos[base + 2];
    px[j] = X; py[j] = Y; pz[j] = Z;
    mx[q] = (double)X; my[q] = (double)Y; mz[q] = (double)Z;
    dist[q] = __builtin_inf();
  }
  if (tid == 0) selstash[b * MB_SEL] = 0.0f;
  __syncthreads();

  int cur = 0;
  for (int k = 1; k < MB_SEL; ++k) {
    double lx = (double)px[cur], ly = (double)py[cur], lz = (double)pz[cur];
    double bestv = -__builtin_inf();
    int    besti = 0x7fffffff;
#pragma unroll
    for (int q = 0; q < 4; ++q) {
      double d2 = d2_np64(mx[q] - lx, my[q] - ly, mz[q] - lz);
      double d  = fmin(dist[q], d2);
      dist[q] = d;
      if (d > bestv) { bestv = d; besti = tid + q * 1024; }  // q asc -> lowest idx on tie
    }
#pragma unroll
    for (int off = 1; off < 64; off <<= 1) {
      double ov = __shfl_xor(bestv, off, 64);
      int    oi = __shfl_xor(besti, off, 64);
      if (ov > bestv || (ov == bestv && oi < besti)) { bestv = ov; besti = oi; }
    }
    if (lane == 0) { redv[wid] = bestv; redi[wid] = besti; }
    __syncthreads();
    if (wid == 0) {
      double v  = (lane < 16) ? redv[lane] : -__builtin_inf();
      int   idx = (lane < 16) ? redi[lane] : 0x7fffffff;
#pragma unroll
      for (int off = 1; off < 16; off <<= 1) {
        double ov = __shfl_xor(v, off, 64);
        int    oi = __shfl_xor(idx, off, 64);
        if (ov > v || (ov == v && oi < idx)) { v = ov; idx = oi; }
      }
      if (lane == 0) { winner = idx; selstash[b * MB_SEL + k] = (float)idx; }
    }
    __syncthreads();
    cur = winner;
  }
}

// ---------------------------------------------------------------------------
// Kernel 2: fused radius (f64 predicate) + PointNetConv MLP (f32) + masked max.
// One 256-thr block per centroid, zero global scratch. All outputs f32.
// ---------------------------------------------------------------------------
template <int CIN, int INSTRIDE>
__device__ __forceinline__ void layer128(const float* __restrict__ in,
                                         const float* __restrict__ W,
                                         const float* __restrict__ bias,
                                         float* __restrict__ out, int tid) {
  const int og = tid & 15;   // o block: 8 outputs
  const int ng = tid >> 4;   // n block: 4 rows
  const int o0 = og * 8;
  float acc[4][8];
  {
    float4 bb0 = *(const float4*)(bias + o0);
    float4 bb1 = *(const float4*)(bias + o0 + 4);
    float bb[8] = {bb0.x, bb0.y, bb0.z, bb0.w, bb1.x, bb1.y, bb1.z, bb1.w};
#pragma unroll
    for (int r = 0; r < 4; ++r)
#pragma unroll
      for (int k = 0; k < 8; ++k) acc[r][k] = bb[k];
  }
  const float* in0 = in + (ng * 4) * INSTRIDE;
#pragma unroll 4
  for (int i = 0; i < CIN; ++i) {
    float4 w0 = *(const float4*)(W + i * 128 + o0);
    float4 w1 = *(const float4*)(W + i * 128 + o0 + 4);
    float w[8] = {w0.x, w0.y, w0.z, w0.w, w1.x, w1.y, w1.z, w1.w};
#pragma unroll
    for (int r = 0; r < 4; ++r) {
      float f = in0[r * INSTRIDE + i];
#pragma unroll
      for (int k = 0; k < 8; ++k) acc[r][k] = fmaf(f, w[k], acc[r][k]);
    }
  }
#pragma unroll
  for (int r = 0; r < 4; ++r) {
    float* orow = out + (ng * 4 + r) * 128 + o0;
#pragma unroll
    for (int k = 0; k < 8; ++k) orow[k] = fmaxf(acc[r][k], 0.f);
  }
}

__global__ __launch_bounds__(256) void conv_kernel(
    const float* __restrict__ x, const float* __restrict__ pos,
    const float* __restrict__ W1, const float* __restrict__ b1,
    const float* __restrict__ W2, const float* __restrict__ b2,
    const float* __restrict__ W3, const float* __restrict__ b3,
    const float* __restrict__ selstash, float* __restrict__ out_x,
    float* __restrict__ out_pos, float* __restrict__ out_batch) {
  __shared__ float A[64 * 128];    // feat (stride 68) / h2 (stride 128)
  __shared__ float Bf[64 * 128];   // h1 (stride 128) / red3 [16][256]
  // overlay scratch in the unused tail of A (feat occupies only [0,4352))
  unsigned long long* masks = (unsigned long long*)(A + 4352);  // 64 x u64
  int* nbrS = (int*)(A + 4480);                                 // 64 ints
  int* nvS  = (int*)(A + 4544);                                 // 1 int

  const int tid  = threadIdx.x;
  const int lane = tid & 63;
  const int wid  = tid >> 6;
  const int c    = blockIdx.x;
  const int b    = c >> 10;
  const int s    = ((int)selstash[c]) & (NB_PTS - 1);  // defensive clamp
  const size_t qb = ((size_t)(b * NB_PTS + s)) * 3;
  const float qxf = pos[qb], qyf = pos[qb + 1], qzf = pos[qb + 2];
  const double qx = (double)qxf, qy = (double)qyf, qz = (double)qzf;
  const double RR = 0.2 * 0.2;   // np's R*R in f64

  // ---- radius phase: in-ball bitmask for all 4096 points (f64 predicate) ----
  for (int it = 0; it < 16; ++it) {
    const int ch = wid * 16 + it;
    const int j  = ch * 64 + lane;
    const size_t pb = ((size_t)b * NB_PTS + j) * 3;
    double d2 = d2_np64((double)pos[pb] - qx, (double)pos[pb + 1] - qy,
                        (double)pos[pb + 2] - qz);
    unsigned long long m = __ballot(d2 <= RR);
    if (lane == 0) masks[ch] = m;
  }
  __syncthreads();

  // ---- wave 0: ordered first-64 extraction via prefix popcount ----
  if (tid < 64) {
    unsigned long long m = masks[tid];
    int pc = __popcll(m);
    int incl = pc;
#pragma unroll
    for (int off = 1; off < 64; off <<= 1) {
      int o = __shfl_up(incl, off, 64);
      if (tid >= off) incl += o;
    }
    int base = incl - pc;                     // exclusive prefix
    int tot  = __shfl(incl, 63, 64);
    int nvw  = min(tot, KNBR);
    if (tid == 63) nvS[0] = nvw;
    int slot = base;
    unsigned long long mm = m;
    while (mm && slot < KNBR) {
      int bit = __ffsll(mm) - 1;
      nbrS[slot++] = tid * 64 + bit;          // ascending global index order
      mm &= mm - 1;
    }
    if (tid >= nvw) nbrS[tid] = s;            // pad (masked out later)
  }
  __syncthreads();
  const int nv = nvS[0];

  // ---- gather feat = [x_j (64), pos_j - pos_i (3)] (f32) ----
  {
    const int n = tid >> 2;      // neighbor slot
    const int part = tid & 3;    // 16 x-feats each
    const int g = nbrS[n];
    const float* xrow = x + (((size_t)(b * NB_PTS + g)) << 6);
    float* fr = A + n * 68 + part * 16;
#pragma unroll
    for (int t = 0; t < 4; ++t) {
      float4 u = *(const float4*)(xrow + part * 16 + t * 4);
      fr[t * 4 + 0] = u.x; fr[t * 4 + 1] = u.y;
      fr[t * 4 + 2] = u.z; fr[t * 4 + 3] = u.w;
    }
    if (part == 0) {
      size_t gb = ((size_t)(b * NB_PTS + g)) * 3;
      float* fr2 = A + n * 68 + 64;
      fr2[0] = pos[gb]     - qxf;
      fr2[1] = pos[gb + 1] - qyf;
      fr2[2] = pos[gb + 2] - qzf;
    }
  }
  __syncthreads();
  layer128<67, 68>(A, W1, b1, Bf, tid);     // feat -> h1
  __syncthreads();
  layer128<128, 128>(Bf, W2, b2, A, tid);   // h1 -> h2 (overlay destroyed, ok)
  __syncthreads();

  // ---- layer 3 (128 -> 256) + ReLU + validity mask + partial max over n ----
  {
    const int og = tid & 15;   // 16 outputs
    const int ng = tid >> 4;   // 4 rows
    const int o0 = og * 16;
    float acc[4][16];
    {
      float bb[16];
#pragma unroll
      for (int t = 0; t < 4; ++t) {
        float4 u = *(const float4*)(b3 + o0 + t * 4);
        bb[t * 4] = u.x; bb[t * 4 + 1] = u.y; bb[t * 4 + 2] = u.z; bb[t * 4 + 3] = u.w;
      }
#pragma unroll
      for (int r = 0; r < 4; ++r)
#pragma unroll
        for (int k = 0; k < 16; ++k) acc[r][k] = bb[k];
    }
    const float* in0 = A + (ng * 4) * 128;
#pragma unroll 2
    for (int i = 0; i < 128; ++i) {
      float w[16];
#pragma unroll
      for (int t = 0; t < 4; ++t) {
        float4 u = *(const float4*)(W3 + i * 256 + o0 + t * 4);
        w[t * 4] = u.x; w[t * 4 + 1] = u.y; w[t * 4 + 2] = u.z; w[t * 4 + 3] = u.w;
      }
#pragma unroll
      for (int r = 0; r < 4; ++r) {
        float f = in0[r * 128 + i];
#pragma unroll
        for (int k = 0; k < 16; ++k) acc[r][k] = fmaf(f, w[k], acc[r][k]);
      }
    }
    float pm[16];
#pragma unroll
    for (int k = 0; k < 16; ++k) pm[k] = -1e9f;
#pragma unroll
    for (int r = 0; r < 4; ++r) {
      const bool val = (ng * 4 + r) < nv;
#pragma unroll
      for (int k = 0; k < 16; ++k) {
        float h = fmaxf(acc[r][k], 0.f);
        pm[k] = fmaxf(pm[k], val ? h : -1e9f);
      }
    }
    float* pr = Bf + ng * 256 + o0;
#pragma unroll
    for (int k = 0; k < 16; ++k) pr[k] = pm[k];
  }
  __syncthreads();
  // ---- final max over the 16 partials; write all three outputs (f32) ----
  {
    float v = Bf[tid];
#pragma unroll
    for (int g2 = 1; g2 < 16; ++g2) v = fmaxf(v, Bf[g2 * 256 + tid]);
    out_x[(size_t)c * 256 + tid] = v;
  }
  if (tid < 3) out_pos[c * 3 + tid] = pos[qb + tid];
  if (tid == 0) out_batch[c] = (float)b;   // overwrite sel stash
}

extern "C" void kernel_launch(void* const* d_in, const int* in_sizes, int n_in,
                              void* d_out, int out_size, void* d_ws, size_t ws_size,
                              hipStream_t stream) {
  const float* x   = (const float*)d_in[0];
  const float* pos = (const float*)d_in[1];
  // d_in[2] = batch (int32) — layout known (arange(N)//NB), unused
  const float* W1 = (const float*)d_in[3];
  const float* b1 = (const float*)d_in[4];
  const float* W2 = (const float*)d_in[5];
  const float* b2 = (const float*)d_in[6];
  const float* W3 = (const float*)d_in[7];
  const float* b3 = (const float*)d_in[8];

  float* out = (float*)d_out;
  float* out_pos   = out + (size_t)NCENT * 256;     // after x_out
  float* out_batch = out_pos + (size_t)NCENT * 3;   // after pos_out
  // sel stashed as exact small floats in the batch_out region (overwritten at
  // the end of conv_kernel). d_ws deliberately unused.

  fps_kernel<<<NCLOUD, 1024, 0, stream>>>(pos, out_batch);
  conv_kernel<<<NCENT, 256, 0, stream>>>(x, pos, W1, b1, W2, b2, W3, b3,
                                         out_batch, out, out_pos, out_batch);
}